// Round 2
// baseline (78.892 us; speedup 1.0000x reference)
//
#include <hip/hip_runtime.h>
#include <math.h>

#define Bb   2
#define Vv   20000
#define Cc   9
#define KS   9
#define OUTn 16
#define NB   16
#define PADC 12           // padded row stride (floats), 48 B, float4-aligned

// Pre-pass: xpad[b][j][0..11] = (j==0 ? 0 : x[b][j-1][0..8]), tail padded 0.
__global__ __launch_bounds__(256) void prepad_kernel(
    const float* __restrict__ x, float* __restrict__ xpad)
{
    int t = blockIdx.x * 256 + threadIdx.x;       // row index over B*(V+1)
    if (t >= Bb * (Vv + 1)) return;
    int b = t / (Vv + 1);
    int j = t - b * (Vv + 1);

    float r[PADC];
    #pragma unroll
    for (int c = 0; c < PADC; ++c) r[c] = 0.0f;
    if (j > 0) {
        const float* src = x + ((size_t)b * Vv + (j - 1)) * Cc;
        #pragma unroll
        for (int c = 0; c < Cc; ++c) r[c] = src[c];
    }
    float4* dst = (float4*)(xpad + (size_t)t * PADC);
    dst[0] = make_float4(r[0], r[1], r[2],  r[3]);
    dst[1] = make_float4(r[4], r[5], r[6],  r[7]);
    dst[2] = make_float4(r[8], r[9], r[10], r[11]);
}

// Main: 4 lanes per (b,v). Each lane: 4 neighbors -> partial s[9][9];
// quad butterfly reduce; each lane emits 4 of the 16 outputs.
__global__ __launch_bounds__(256) void nlayer_kernel(
    const float* __restrict__ xpad,   // (B, V+1, PADC)
    const float* __restrict__ W,      // (C,KS,OUT)
    const int*   __restrict__ adj,    // (V,NB)
    float* __restrict__ out)          // (B,V,OUT)
{
    __shared__ float sW[Cc * KS * OUTn];
    for (int i = threadIdx.x; i < Cc * KS * OUTn; i += 256) sW[i] = W[i];
    __syncthreads();

    int t    = blockIdx.x * 256 + threadIdx.x;
    int pair = t >> 2;                 // which (b,v)
    int sub  = t & 3;                  // lane within quad
    if (pair >= Bb * Vv) return;
    int b = pair / Vv;
    int v = pair - b * Vv;

    const float* xb = xpad + (size_t)b * (Vv + 1) * PADC;

    // center row (all 4 lanes same address -> broadcast)
    const float4* xvp = (const float4*)(xb + (size_t)(v + 1) * PADC);
    float4 xv0 = xvp[0], xv1 = xvp[1];
    float  xv8 = ((const float*)&xvp[2])[0];
    float xv[Cc] = {xv0.x, xv0.y, xv0.z, xv0.w, xv1.x, xv1.y, xv1.z, xv1.w, xv8};

    // this lane's 4 neighbors (16B-aligned int4)
    int4 av = *(const int4*)(adj + (size_t)v * NB + (sub << 2));
    int a[4] = {av.x, av.y, av.z, av.w};

    int deg = 0;
    #pragma unroll
    for (int i = 0; i < 4; ++i) deg += (a[i] != 0);

    float s[KS][Cc];
    #pragma unroll
    for (int k = 0; k < KS; ++k)
        #pragma unroll
        for (int c = 0; c < Cc; ++c) s[k][c] = 0.0f;

    #pragma unroll
    for (int i = 0; i < 4; ++i) {
        int j = a[i];                         // j==0 -> zeros row -> s += q*0
        const float4* np = (const float4*)(xb + (size_t)j * PADC);
        float4 n0 = np[0], n1 = np[1];
        float  n8 = ((const float*)&np[2])[0];
        float xn[Cc] = {n0.x, n0.y, n0.z, n0.w, n1.x, n1.y, n1.z, n1.w, n8};

        float d[Cc];
        float m = -INFINITY;
        #pragma unroll
        for (int c = 0; c < Cc; ++c) { d[c] = xv[c] - xn[c]; m = fmaxf(m, d[c]); }
        float e[Cc];
        float sum = 0.0f;
        #pragma unroll
        for (int c = 0; c < Cc; ++c) { e[c] = __expf(d[c] - m); sum += e[c]; }
        float inv = 1.0f / sum;

        #pragma unroll
        for (int k = 0; k < KS; ++k) {
            float qk = e[k] * inv;
            #pragma unroll
            for (int c = 0; c < Cc; ++c) s[k][c] = fmaf(qk, xn[c], s[k][c]);
        }
    }

    // quad reduction: lanes {0,1,2,3} of each quad sum their partials
    #pragma unroll
    for (int k = 0; k < KS; ++k) {
        #pragma unroll
        for (int c = 0; c < Cc; ++c) {
            float vv = s[k][c];
            vv += __shfl_xor(vv, 1);
            vv += __shfl_xor(vv, 2);
            s[k][c] = vv;
        }
    }
    deg += __shfl_xor(deg, 1);
    deg += __shfl_xor(deg, 2);
    float invdeg = (deg > 0) ? (1.0f / (float)deg) : 0.0f;

    // epilogue: this lane computes outputs [sub*4, sub*4+4)
    float acc0 = 0.f, acc1 = 0.f, acc2 = 0.f, acc3 = 0.f;
    #pragma unroll
    for (int c = 0; c < Cc; ++c) {
        #pragma unroll
        for (int k = 0; k < KS; ++k) {
            float sv = s[k][c];
            float4 w = *(const float4*)&sW[(c * KS + k) * OUTn + (sub << 2)];
            acc0 = fmaf(sv, w.x, acc0);
            acc1 = fmaf(sv, w.y, acc1);
            acc2 = fmaf(sv, w.z, acc2);
            acc3 = fmaf(sv, w.w, acc3);
        }
    }

    float4 r;
    r.x = fmaxf(acc0 * invdeg, 0.0f);
    r.y = fmaxf(acc1 * invdeg, 0.0f);
    r.z = fmaxf(acc2 * invdeg, 0.0f);
    r.w = fmaxf(acc3 * invdeg, 0.0f);
    *(float4*)(out + (size_t)pair * OUTn + (sub << 2)) = r;
}

extern "C" void kernel_launch(void* const* d_in, const int* in_sizes, int n_in,
                              void* d_out, int out_size, void* d_ws, size_t ws_size,
                              hipStream_t stream) {
    const float* x   = (const float*)d_in[0];
    const float* W   = (const float*)d_in[1];
    const int*   adj = (const int*)d_in[2];
    float*       out = (float*)d_out;
    float*       xpad = (float*)d_ws;        // B*(V+1)*PADC floats = 1.92 MB

    {
        int total = Bb * (Vv + 1);
        prepad_kernel<<<(total + 255) / 256, 256, 0, stream>>>(x, xpad);
    }
    {
        int total = Bb * Vv * 4;             // 4 lanes per (b,v)
        nlayer_kernel<<<(total + 255) / 256, 256, 0, stream>>>(xpad, W, adj, out);
    }
}

// Round 3
// 75.139 us; speedup vs baseline: 1.0499x; 1.0499x over previous
//
#include <hip/hip_runtime.h>
#include <math.h>

#define Bb   2
#define Vv   20000
#define Cc   9
#define KS   9
#define OUTn 16
#define NB   16

// Single fused kernel: 4 lanes per (b,v). Each lane handles 4 neighbors
// (partial s[9][9]), quad DPP-shuffle reduce, each lane emits 4 outputs.
// adj==0 handled branchlessly: clamp row index, zero the row via mask ->
// softmax(q) multiplies xn==0, contributing exactly 0 to s (matches ref).
__global__ __launch_bounds__(256) void nlayer_kernel(
    const float* __restrict__ x,      // (B,V,C)
    const float* __restrict__ W,      // (C,KS,OUT)
    const int*   __restrict__ adj,    // (V,NB)
    float* __restrict__ out)          // (B,V,OUT)
{
    __shared__ float sW[Cc * KS * OUTn];   // 5184 B
    for (int i = threadIdx.x; i < Cc * KS * OUTn; i += 256) sW[i] = W[i];
    __syncthreads();

    int t    = blockIdx.x * 256 + threadIdx.x;
    int pair = t >> 2;                 // which (b,v)
    int sub  = t & 3;                  // lane within quad
    if (pair >= Bb * Vv) return;
    int b = pair / Vv;
    int v = pair - b * Vv;

    const float* xb = x + (size_t)b * Vv * Cc;

    // center row (same address across quad -> broadcast)
    float xv[Cc];
    #pragma unroll
    for (int c = 0; c < Cc; ++c) xv[c] = xb[(size_t)v * Cc + c];

    // this lane's 4 neighbors (16B-aligned int4)
    int4 av = *(const int4*)(adj + (size_t)v * NB + (sub << 2));
    int a[4] = {av.x, av.y, av.z, av.w};

    int deg = 0;
    #pragma unroll
    for (int i = 0; i < 4; ++i) deg += (a[i] != 0);

    float s[KS][Cc];
    #pragma unroll
    for (int k = 0; k < KS; ++k)
        #pragma unroll
        for (int c = 0; c < Cc; ++c) s[k][c] = 0.0f;

    #pragma unroll
    for (int i = 0; i < 4; ++i) {
        int j = a[i];
        int row   = (j > 0) ? (j - 1) : 0;     // clamp: safe address
        float msk = (j > 0) ? 1.0f : 0.0f;     // zero the row if masked
        const float* xp = xb + (size_t)row * Cc;

        float xn[Cc];
        #pragma unroll
        for (int c = 0; c < Cc; ++c) xn[c] = xp[c] * msk;

        float d[Cc];
        float m = -INFINITY;
        #pragma unroll
        for (int c = 0; c < Cc; ++c) { d[c] = xv[c] - xn[c]; m = fmaxf(m, d[c]); }
        float e[Cc];
        float sum = 0.0f;
        #pragma unroll
        for (int c = 0; c < Cc; ++c) { e[c] = __expf(d[c] - m); sum += e[c]; }
        float inv = 1.0f / sum;

        #pragma unroll
        for (int k = 0; k < KS; ++k) {
            float qk = e[k] * inv;
            #pragma unroll
            for (int c = 0; c < Cc; ++c) s[k][c] = fmaf(qk, xn[c], s[k][c]);
        }
    }

    // quad reduction (xor 1, xor 2) — compiles to cheap DPP cross-lane adds
    #pragma unroll
    for (int k = 0; k < KS; ++k) {
        #pragma unroll
        for (int c = 0; c < Cc; ++c) {
            float vv = s[k][c];
            vv += __shfl_xor(vv, 1);
            vv += __shfl_xor(vv, 2);
            s[k][c] = vv;
        }
    }
    deg += __shfl_xor(deg, 1);
    deg += __shfl_xor(deg, 2);
    float invdeg = (deg > 0) ? (1.0f / (float)deg) : 0.0f;

    // epilogue: this lane computes outputs [sub*4, sub*4+4)
    float acc0 = 0.f, acc1 = 0.f, acc2 = 0.f, acc3 = 0.f;
    #pragma unroll
    for (int c = 0; c < Cc; ++c) {
        #pragma unroll
        for (int k = 0; k < KS; ++k) {
            float sv = s[k][c];
            float4 w = *(const float4*)&sW[(c * KS + k) * OUTn + (sub << 2)];
            acc0 = fmaf(sv, w.x, acc0);
            acc1 = fmaf(sv, w.y, acc1);
            acc2 = fmaf(sv, w.z, acc2);
            acc3 = fmaf(sv, w.w, acc3);
        }
    }

    float4 r;
    r.x = fmaxf(acc0 * invdeg, 0.0f);
    r.y = fmaxf(acc1 * invdeg, 0.0f);
    r.z = fmaxf(acc2 * invdeg, 0.0f);
    r.w = fmaxf(acc3 * invdeg, 0.0f);
    *(float4*)(out + (size_t)pair * OUTn + (sub << 2)) = r;
}

extern "C" void kernel_launch(void* const* d_in, const int* in_sizes, int n_in,
                              void* d_out, int out_size, void* d_ws, size_t ws_size,
                              hipStream_t stream) {
    const float* x   = (const float*)d_in[0];
    const float* W   = (const float*)d_in[1];
    const int*   adj = (const int*)d_in[2];
    float*       out = (float*)d_out;

    const int total = Bb * Vv * 4;           // 4 lanes per (b,v)
    const int block = 256;
    const int grid  = (total + block - 1) / block;
    nlayer_kernel<<<grid, block, 0, stream>>>(x, W, adj, out);
}